// Round 4
// baseline (500.096 us; speedup 1.0000x reference)
//
#include <hip/hip_runtime.h>

typedef unsigned short ushort_t;
typedef unsigned char uchar_t;
typedef __attribute__((ext_vector_type(8))) __bf16 bf16x8;
typedef __attribute__((ext_vector_type(4))) float f32x4;
typedef __attribute__((ext_vector_type(8))) unsigned short u16x8;
typedef __attribute__((ext_vector_type(8))) int i32x8;

#define NB 32
#define TT 12
#define NNODE 1024
#define FF 64
#define OO 64
#define TO 768   // TT*OO

#define SCL_ONE 127   // e8m0 2^0

__device__ __forceinline__ unsigned short f2bf(float f) {
    unsigned u = __float_as_uint(f);
    u += 0x7FFFu + ((u >> 16) & 1u);           // RNE
    return (unsigned short)(u >> 16);
}
__device__ __forceinline__ float bf2f(unsigned short h) {
    return __uint_as_float(((unsigned)h) << 16);
}
__device__ __forceinline__ unsigned char f2fp8(float f) {
    return (unsigned char)(__builtin_amdgcn_cvt_pk_fp8_f32(f, f, 0, false) & 0xff);
}

// async global->LDS, 16B/lane; LDS dest = wave-uniform base + lane*16
__device__ __forceinline__ void gload16(const void* g, void* l) {
    __builtin_amdgcn_global_load_lds(
        (const __attribute__((address_space(1))) unsigned int*)g,
        (__attribute__((address_space(3))) unsigned int*)l, 16, 0, 0);
}

// ---------------------------------------------------------------- lambda init
__global__ void k_init(unsigned* lam) {
    if (threadIdx.x < NB) lam[threadIdx.x] = 0x3F800000u;  // 1.0f clamp
}

// --------------- fused single-pass over A: E8 = fp8(2*A)  +  lam = max rowsum
// E8 is now batch-independent (lambda folded into GEMM epilogues as 1/lam),
// which removes the rowmax->escale dependency and the second 128 MiB A read.
// Block = 256 thr * 8 floats = 2048 floats = exactly 2 rows of A.
// Wave w covers a half-row: waves {0,1} = row0, {2,3} = row1.
__global__ __launch_bounds__(256) void k_prep(const float* __restrict__ A,
                                              unsigned* __restrict__ lam,
                                              uchar_t* __restrict__ E8) {
    __shared__ float ls[4];
    const size_t idx = ((size_t)blockIdx.x * 256 + threadIdx.x) * 8;
    const int b = (int)(idx >> 20);
    const float4 v0 = *(const float4*)(A + idx);
    const float4 v1 = *(const float4*)(A + idx + 4);
    unsigned lo = 0, hi = 0;
    lo = (unsigned)__builtin_amdgcn_cvt_pk_fp8_f32(v0.x * 2.0f, v0.y * 2.0f, (int)lo, false);
    lo = (unsigned)__builtin_amdgcn_cvt_pk_fp8_f32(v0.z * 2.0f, v0.w * 2.0f, (int)lo, true);
    hi = (unsigned)__builtin_amdgcn_cvt_pk_fp8_f32(v1.x * 2.0f, v1.y * 2.0f, (int)hi, false);
    hi = (unsigned)__builtin_amdgcn_cvt_pk_fp8_f32(v1.z * 2.0f, v1.w * 2.0f, (int)hi, true);
    uint2 pk; pk.x = lo; pk.y = hi;
    *(uint2*)(E8 + idx) = pk;
    float s = v0.x + v0.y + v0.z + v0.w + v1.x + v1.y + v1.z + v1.w;
#pragma unroll
    for (int off = 32; off > 0; off >>= 1) s += __shfl_down(s, off, 64);
    const int w = threadIdx.x >> 6;
    if ((threadIdx.x & 63) == 0) ls[w] = s;
    __syncthreads();
    if (threadIdx.x == 0) {
        const float r0 = ls[0] + ls[1], r1 = ls[2] + ls[3];
        atomicMax(&lam[b], __float_as_uint(fmaxf(r0, r1)));
    }
}

// ------------------------- Theta [3][64 f][64 o] fp32 -> Tht [3][64 o][64 f] bf16
__global__ void k_theta(const float* __restrict__ Th, ushort_t* __restrict__ Tht) {
    int tid = blockIdx.x * 256 + threadIdx.x;
    if (tid < 3 * 64 * 64) {
        int k = tid >> 12, rem = tid & 4095, o = rem >> 6, f = rem & 63;
        Tht[tid] = f2bf(Th[(k << 12) + (f << 6) + o]);
    }
}

// ----------------- feature transform: Rk = x@Theta_k  (bf16 MFMA / fp32 acc)
// 512 threads, 128-node tile. Theta in LDS (swizzled), x direct from global.
// writes: Pb[b,t,n,o]     = bf16(R0 - R2)      (row-major)
//         Qc[b][c][n]     = bf16(R1 - 2*R2)    (col-major, k=n contiguous)
//         R2f8[b][c][n]   = fp8(R2)            (col-major)
__global__ __launch_bounds__(512, 5) void k_feature(const float* __restrict__ x,
                                                    const ushort_t* __restrict__ Tht,
                                                    ushort_t* __restrict__ Pb,
                                                    ushort_t* __restrict__ Qc,
                                                    uchar_t* __restrict__ R2f8) {
    __shared__ __align__(16) uchar_t th[3 * 64 * 128];    // 24576 B, [ko][f], 16B-chunk swizzled
    __shared__ __align__(16) uchar_t tbuf[26624];         // Q: 64*136 u16 (17408) + R2: 64*144 u8 (9216)
    ushort_t* tbq = (ushort_t*)tbuf;
    char* tbr = (char*)(tbuf + 17408);

    const int n0 = blockIdx.x * 128;
    const int t = blockIdx.y;
    const int b = blockIdx.z;
    const int tid = threadIdx.x;
    const int w = tid >> 6, lane = tid & 63, quad = lane >> 4, l15 = lane & 15;

    // Theta -> LDS, 16B chunks, phys chunk = c ^ (row&7) to break l15-stride-128B aliasing
#pragma unroll
    for (int i = 0; i < 3; ++i) {
        int chunk = i * 512 + tid;            // 0..1535
        int ko = chunk >> 3, c = chunk & 7;
        int phys = c ^ (ko & 7);
        const int4 v = *(const int4*)(Tht + ko * 64 + c * 8);
        *(int4*)(th + ko * 128 + phys * 16) = v;
    }

    // A-frags straight from global (row = n0 + w*16 + l15), fp32 -> bf16 in regs
    const float* xr = x + (((size_t)b * TT + t) * NNODE + n0 + w * 16 + l15) * FF;
    bf16x8 af[2];
#pragma unroll
    for (int ks = 0; ks < 2; ++ks) {
        const float4 v0 = *(const float4*)(xr + ks * 32 + quad * 8);
        const float4 v1 = *(const float4*)(xr + ks * 32 + quad * 8 + 4);
        u16x8 p;
        p[0] = f2bf(v0.x); p[1] = f2bf(v0.y); p[2] = f2bf(v0.z); p[3] = f2bf(v0.w);
        p[4] = f2bf(v1.x); p[5] = f2bf(v1.y); p[6] = f2bf(v1.z); p[7] = f2bf(v1.w);
        af[ks] = *(bf16x8*)&p;
    }
    __syncthreads();

    f32x4 acc[3][4];
#pragma unroll
    for (int k = 0; k < 3; ++k)
#pragma unroll
        for (int cb = 0; cb < 4; ++cb) acc[k][cb] = (f32x4){0.f, 0.f, 0.f, 0.f};

#pragma unroll
    for (int k = 0; k < 3; ++k)
#pragma unroll
        for (int ks = 0; ks < 2; ++ks)
#pragma unroll
            for (int cb = 0; cb < 4; ++cb) {
                const int o = cb * 16 + l15;
                const int c = (ks * 4 + quad) ^ (o & 7);
                const bf16x8 bfr = *(const bf16x8*)(th + (k * 64 + o) * 128 + c * 16);
                acc[k][cb] = __builtin_amdgcn_mfma_f32_16x16x32_bf16(af[ks], bfr, acc[k][cb], 0, 0, 0);
            }

    // P = R0 - R2, row-major (16 x 2B stores/lane, 32B segments per l15-group)
    ushort_t* Pbb = Pb + (((size_t)b * TT + t) * NNODE + n0) * OO;
#pragma unroll
    for (int cb = 0; cb < 4; ++cb)
#pragma unroll
        for (int r = 0; r < 4; ++r) {
            const int n = w * 16 + quad * 4 + r;
            const int o = cb * 16 + l15;
            Pbb[(size_t)n * OO + o] = f2bf(acc[0][cb][r] - acc[2][cb][r]);
        }

    // Q and R2 transposes, single LDS phase
#pragma unroll
    for (int cb = 0; cb < 4; ++cb)
#pragma unroll
        for (int r = 0; r < 4; ++r) {
            const int nl = w * 16 + quad * 4 + r;
            const int o = cb * 16 + l15;
            tbq[o * 136 + nl] = f2bf(acc[1][cb][r] - 2.0f * acc[2][cb][r]);
            tbr[o * 144 + nl] = (char)f2fp8(acc[2][cb][r]);
        }
    __syncthreads();

    {   // stream out: 8 threads per o-row
        const int o = tid >> 3, seg = tid & 7;
        ushort_t* qrow = Qc + ((size_t)b * TO + t * 64 + o) * NNODE + n0 + seg * 16;
        const ushort_t* sq = tbq + o * 136 + seg * 16;
        *(u16x8*)(qrow) = *(const u16x8*)(sq);
        *(u16x8*)(qrow + 8) = *(const u16x8*)(sq + 8);
        uchar_t* rrow = R2f8 + ((size_t)b * TO + t * 64 + o) * NNODE + n0 + seg * 16;
        *(int4*)rrow = *(const int4*)(tbr + o * 144 + seg * 16);
    }
}

// ------------------------------------------------------------- MX-fp8 GEMM
// D[r][c] = sum_k Aop[b][r][k] * Bop[b][c][k], both fp8 k-contiguous.
// E8 now holds 2*A (batch-independent); lambda applied in the epilogue:
//   mode1: W = Q + (2/lam) * acc ;  mode2: out = relu(Pb + (1/lam) * acc).
// Both MX scale operands are 2^0.
// 1-D grid, XCD swizzle: bid%8 = XCD; all 48 tiles of a batch on one XCD.
// LDS 48 KB -> 3 blocks/CU (12 waves): A single-buffered, B double-buffered.
// Per K-step: stage B(kk+1) -> vmcnt(4) [retires A(kk),B(kk)] -> bar ->
//   ds_read A/B -> lgkmcnt(0) -> bar [all waves' reads done] ->
//   stage A(kk+1) into Abuf (lands under MFMA) -> MFMA.
// MODE 1 (W build):  r=c (768 rows), c=n.  A=R2f8, B=E8.
//    w = Qc[c][n] + (2/lam)*D;  Zf8[c][n] = fp8(w);  Pb -= w
// MODE 2 (output):   r=n (1024 rows), c=c.    A=E8, B=Zf8.
//    out = relu(bf16(Pb) + (1/lam)*D)   (Pb already holds P - W; D = (2A)@W)
template <int MODE>
__global__ __launch_bounds__(256, 3) void k_gemm8(const uchar_t* __restrict__ Aop, size_t aBS,
                                                  const uchar_t* __restrict__ Bop, size_t bBS,
                                                  const unsigned* __restrict__ lam,
                                                  const ushort_t* __restrict__ Qc,
                                                  uchar_t* __restrict__ Zf8,
                                                  ushort_t* __restrict__ Pbp,
                                                  float* __restrict__ outp) {
    __shared__ __align__(16) uchar_t smem[49152];   // A 16K @0, B0 16K @16K, B1 16K @32K; epi tb 34816
    const int bid = blockIdx.x;
    const int xcd = bid & 7, y = bid >> 3;
    const int tile = y % 48;
    const int b = xcd + 8 * (y / 48);
    const int tm = (MODE == 1) ? (tile >> 3) : (tile / 6);
    const int tn = (MODE == 1) ? (tile & 7) : (tile % 6);
    const int m0 = tm * 128, n0 = tn * 128;
    const int tid = threadIdx.x;
    const int w = tid >> 6, lane = tid & 63, quad = lane >> 4, l15 = lane & 15;
    const int wr = w >> 1, wc = w & 1;
    const uchar_t* Ab = Aop + (size_t)b * aBS + (size_t)m0 * NNODE;
    const uchar_t* Bb = Bop + (size_t)b * bBS + (size_t)n0 * NNODE;
    const float lamf = __uint_as_float(lam[b]);

    // staging: 16KB per tile, XOR-swizzled 16B chunks (phys = log ^ (row&7))
    int ldso[4];
    size_t goff[4];
#pragma unroll
    for (int i = 0; i < 4; ++i) {
        int slot = i * 256 + tid;
        int row = slot >> 3;
        int lc = (slot & 7) ^ (row & 7);
        ldso[i] = slot * 16;
        goff[i] = (size_t)row * NNODE + lc * 16;
    }

    f32x4 acc[4][4];
#pragma unroll
    for (int i = 0; i < 4; ++i)
#pragma unroll
        for (int j = 0; j < 4; ++j) acc[i][j] = (f32x4){0.f, 0.f, 0.f, 0.f};

    // prologue: A0 first, then B0 (vmcnt retire order relies on this)
#pragma unroll
    for (int i = 0; i < 4; ++i) gload16(Ab + goff[i], smem + ldso[i]);
#pragma unroll
    for (int i = 0; i < 4; ++i) gload16(Bb + goff[i], smem + 16384 + ldso[i]);

#pragma unroll
    for (int kk = 0; kk < 8; ++kk) {
        const uchar_t* At = smem;
        const uchar_t* Bt = smem + 16384 + ((kk & 1) << 14);
        uchar_t* Btn = smem + 16384 + (((kk & 1) ^ 1) << 14);
        if (kk < 7) {
            const int k0 = (kk + 1) << 7;
#pragma unroll
            for (int i = 0; i < 4; ++i) gload16(Bb + k0 + goff[i], Btn + ldso[i]);
            // outstanding: [B(kk):4][A(kk):4][B(kk+1):4] -> retire first 8
            asm volatile("s_waitcnt vmcnt(4)" ::: "memory");
        } else {
            asm volatile("s_waitcnt vmcnt(0)" ::: "memory");
        }
        __builtin_amdgcn_s_barrier();   // tile kk fully resident across all waves

        i32x8 af[4], bfr[4];
#pragma unroll
        for (int i = 0; i < 4; ++i) {
            const int m = wr * 64 + i * 16 + l15;
            const int n = wc * 64 + i * 16 + l15;
            const int4 alo = *(const int4*)(At + m * 128 + (((quad << 1)) ^ (m & 7)) * 16);
            const int4 ahi = *(const int4*)(At + m * 128 + (((quad << 1) | 1) ^ (m & 7)) * 16);
            const int4 blo = *(const int4*)(Bt + n * 128 + (((quad << 1)) ^ (n & 7)) * 16);
            const int4 bhi = *(const int4*)(Bt + n * 128 + (((quad << 1) | 1) ^ (n & 7)) * 16);
            af[i] = (i32x8){alo.x, alo.y, alo.z, alo.w, ahi.x, ahi.y, ahi.z, ahi.w};
            bfr[i] = (i32x8){blo.x, blo.y, blo.z, blo.w, bhi.x, bhi.y, bhi.z, bhi.w};
        }
        asm volatile("s_waitcnt lgkmcnt(0)" ::: "memory");
        __builtin_amdgcn_s_barrier();   // ALL waves' ds_reads done -> Abuf free
        if (kk < 7) {                   // restage A under the MFMA cluster
            const int k0 = (kk + 1) << 7;
#pragma unroll
            for (int i = 0; i < 4; ++i) gload16(Ab + k0 + goff[i], smem + ldso[i]);
        }
        __builtin_amdgcn_s_setprio(1);
#pragma unroll
        for (int i = 0; i < 4; ++i)
#pragma unroll
            for (int j = 0; j < 4; ++j)
                acc[i][j] = __builtin_amdgcn_mfma_scale_f32_16x16x128_f8f6f4(
                    af[i], bfr[j], acc[i][j], 0, 0, 0, SCL_ONE, 0, SCL_ONE);
        __builtin_amdgcn_s_setprio(0);
    }
    __syncthreads();   // epilogue reuses smem (tb overlaps buffers)

    if (MODE == 1) {
        const float c1 = 2.0f / lamf;
        ushort_t* tb = (ushort_t*)smem;   // [n_loc][c_loc], stride 136 (34816 B, fits)
        const ushort_t* Qb = Qc + (size_t)b * TO * NNODE;
        uchar_t* Zb = Zf8 + (size_t)b * TO * NNODE;
#pragma unroll
        for (int i = 0; i < 4; ++i)
#pragma unroll
            for (int r = 0; r < 4; ++r) {
                const int cl = wr * 64 + i * 16 + quad * 4 + r;
                const int c = m0 + cl;
#pragma unroll
                for (int j = 0; j < 4; ++j) {
                    const int nl = wc * 64 + j * 16 + l15;
                    const size_t zi = (size_t)c * NNODE + n0 + nl;
                    const float z = bf2f(Qb[zi]) + c1 * acc[i][j][r];
                    Zb[zi] = f2fp8(z);
                    tb[nl * 136 + cl] = f2bf(z);
                }
            }
        __syncthreads();
        // coalesced Pb -= w : each thread handles one (n-row, t-half) 128B segment
        const int t0 = m0 >> 6;
        const int row = tid >> 1, half = tid & 1;
        ushort_t* prow = Pbp + (((size_t)b * TT + t0 + half) * NNODE + n0 + row) * OO;
        const ushort_t* srow = tb + row * 136 + half * 64;
#pragma unroll
        for (int s = 0; s < 8; ++s) {
            u16x8 pv = *(const u16x8*)(prow + s * 8);
            u16x8 zv = *(const u16x8*)(srow + s * 8);
            u16x8 rv;
#pragma unroll
            for (int e = 0; e < 8; ++e) rv[e] = f2bf(bf2f(pv[e]) - bf2f(zv[e]));
            *(u16x8*)(prow + s * 8) = rv;
        }
    } else {
        const float c2 = 1.0f / lamf;
#pragma unroll
        for (int i = 0; i < 4; ++i)
#pragma unroll
            for (int r = 0; r < 4; ++r) {
                const int n = m0 + wr * 64 + i * 16 + quad * 4 + r;
#pragma unroll
                for (int j = 0; j < 4; ++j) {
                    const int c = n0 + wc * 64 + j * 16 + l15;
                    const int t = c >> 6, o = c & 63;
                    const size_t id = (((size_t)b * TT + t) * NNODE + n) * OO + o;
                    outp[id] = fmaxf(bf2f(Pbp[id]) + c2 * acc[i][j][r], 0.0f);
                }
            }
    }
}

extern "C" void kernel_launch(void* const* d_in, const int* in_sizes, int n_in,
                              void* d_out, int out_size, void* d_ws, size_t ws_size,
                              hipStream_t stream) {
    const float* x = (const float*)d_in[0];
    const float* A = (const float*)d_in[1];
    const float* Th = (const float*)d_in[2];
    float* out = (float*)d_out;
    char* ws = (char*)d_ws;

    // workspace (~176 MiB)
    unsigned* lam = (unsigned*)ws;                                   // 256 B
    uchar_t* E8 = (uchar_t*)(ws + 256);                              // 32 MiB
    uchar_t* R2f8 = E8 + (size_t)NB * NNODE * NNODE;                 // 24 MiB
    uchar_t* Zf8 = R2f8 + (size_t)NB * TO * NNODE;                   // 24 MiB
    ushort_t* Qc = (ushort_t*)(Zf8 + (size_t)NB * TO * NNODE);       // 48 MiB
    ushort_t* Pb = Qc + (size_t)NB * TO * NNODE;                     // 48 MiB
    ushort_t* Tht = Pb + (size_t)NB * TT * NNODE * OO;               // 24 KiB

    k_init<<<1, 64, 0, stream>>>(lam);
    k_prep<<<16384, 256, 0, stream>>>(A, lam, E8);
    k_theta<<<48, 256, 0, stream>>>(Th, Tht);
    k_feature<<<dim3(8, 12, 32), 512, 0, stream>>>(x, Tht, Pb, Qc, R2f8);
    k_gemm8<1><<<1536, 256, 0, stream>>>(R2f8, (size_t)TO * NNODE,
                                         E8, (size_t)NNODE * NNODE,
                                         lam, Qc, Zf8, Pb, nullptr);
    k_gemm8<2><<<1536, 256, 0, stream>>>(E8, (size_t)NNODE * NNODE,
                                         Zf8, (size_t)TO * NNODE,
                                         lam, nullptr, nullptr, Pb, out);
}

// Round 5
// 401.801 us; speedup vs baseline: 1.2446x; 1.2446x over previous
//
#include <hip/hip_runtime.h>

typedef unsigned short ushort_t;
typedef unsigned char uchar_t;
typedef __attribute__((ext_vector_type(8))) __bf16 bf16x8;
typedef __attribute__((ext_vector_type(4))) float f32x4;
typedef __attribute__((ext_vector_type(8))) unsigned short u16x8;
typedef __attribute__((ext_vector_type(8))) int i32x8;

#define NB 32
#define TT 12
#define NNODE 1024
#define FF 64
#define OO 64
#define TO 768   // TT*OO

#define SCL_ONE 127   // e8m0 2^0

__device__ __forceinline__ unsigned short f2bf(float f) {
    unsigned u = __float_as_uint(f);
    u += 0x7FFFu + ((u >> 16) & 1u);           // RNE
    return (unsigned short)(u >> 16);
}
__device__ __forceinline__ float bf2f(unsigned short h) {
    return __uint_as_float(((unsigned)h) << 16);
}
__device__ __forceinline__ unsigned char f2fp8(float f) {
    return (unsigned char)(__builtin_amdgcn_cvt_pk_fp8_f32(f, f, 0, false) & 0xff);
}

// async global->LDS, 16B/lane; LDS dest = wave-uniform base + lane*16
__device__ __forceinline__ void gload16(const void* g, void* l) {
    __builtin_amdgcn_global_load_lds(
        (const __attribute__((address_space(1))) unsigned int*)g,
        (__attribute__((address_space(3))) unsigned int*)l, 16, 0, 0);
}

// --------------- fused single-pass over A: E8 = fp8(2*A)  +  per-row sums
// E8 is batch-independent (lambda folded into GEMM epilogues as 1/lam).
// NO atomics: block writes its 2 row-sums to rsum[] with plain stores
// (R4's 16384 same-cache-line atomicMax serialized at ~150 us).
// Block = 256 thr * 8 floats = 2048 floats = exactly 2 rows of A.
// Waves {0,1} cover row 2*bid, waves {2,3} cover row 2*bid+1.
__global__ __launch_bounds__(256) void k_prep(const float* __restrict__ A,
                                              float* __restrict__ rsum,
                                              uchar_t* __restrict__ E8) {
    __shared__ float ls[4];
    const size_t idx = ((size_t)blockIdx.x * 256 + threadIdx.x) * 8;
    const float4 v0 = *(const float4*)(A + idx);
    const float4 v1 = *(const float4*)(A + idx + 4);
    unsigned lo = 0, hi = 0;
    lo = (unsigned)__builtin_amdgcn_cvt_pk_fp8_f32(v0.x * 2.0f, v0.y * 2.0f, (int)lo, false);
    lo = (unsigned)__builtin_amdgcn_cvt_pk_fp8_f32(v0.z * 2.0f, v0.w * 2.0f, (int)lo, true);
    hi = (unsigned)__builtin_amdgcn_cvt_pk_fp8_f32(v1.x * 2.0f, v1.y * 2.0f, (int)hi, false);
    hi = (unsigned)__builtin_amdgcn_cvt_pk_fp8_f32(v1.z * 2.0f, v1.w * 2.0f, (int)hi, true);
    uint2 pk; pk.x = lo; pk.y = hi;
    *(uint2*)(E8 + idx) = pk;
    float s = v0.x + v0.y + v0.z + v0.w + v1.x + v1.y + v1.z + v1.w;
#pragma unroll
    for (int off = 32; off > 0; off >>= 1) s += __shfl_down(s, off, 64);
    const int w = threadIdx.x >> 6;
    if ((threadIdx.x & 63) == 0) ls[w] = s;
    __syncthreads();
    if (threadIdx.x == 0) {
        rsum[blockIdx.x * 2]     = ls[0] + ls[1];
        rsum[blockIdx.x * 2 + 1] = ls[2] + ls[3];
    }
}

// --------------- lam[b] = max(1, max_n rsum[b][n])  (32 blocks, 128 KB read)
__global__ __launch_bounds__(256) void k_lmax(const float* __restrict__ rsum,
                                              unsigned* __restrict__ lam) {
    __shared__ float ls[4];
    const int b = blockIdx.x;
    const float4 v = *(const float4*)(rsum + b * NNODE + threadIdx.x * 4);
    float m = fmaxf(fmaxf(v.x, v.y), fmaxf(v.z, v.w));
#pragma unroll
    for (int off = 32; off > 0; off >>= 1) m = fmaxf(m, __shfl_down(m, off, 64));
    const int w = threadIdx.x >> 6;
    if ((threadIdx.x & 63) == 0) ls[w] = m;
    __syncthreads();
    if (threadIdx.x == 0) {
        const float r = fmaxf(fmaxf(ls[0], ls[1]), fmaxf(ls[2], ls[3]));
        lam[b] = __float_as_uint(fmaxf(r, 1.0f));
    }
}

// ------------------------- Theta [3][64 f][64 o] fp32 -> Tht [3][64 o][64 f] bf16
__global__ void k_theta(const float* __restrict__ Th, ushort_t* __restrict__ Tht) {
    int tid = blockIdx.x * 256 + threadIdx.x;
    if (tid < 3 * 64 * 64) {
        int k = tid >> 12, rem = tid & 4095, o = rem >> 6, f = rem & 63;
        Tht[tid] = f2bf(Th[(k << 12) + (f << 6) + o]);
    }
}

// ----------------- feature transform: Rk = x@Theta_k  (bf16 MFMA / fp32 acc)
// 512 threads, 128-node tile. Theta in LDS (swizzled), x direct from global.
// writes: Pb[b,t,n,o]     = bf16(R0 - R2)      (row-major)
//         Qc[b][c][n]     = bf16(R1 - 2*R2)    (col-major, k=n contiguous)
//         R2f8[b][c][n]   = fp8(R2)            (col-major)
__global__ __launch_bounds__(512, 5) void k_feature(const float* __restrict__ x,
                                                    const ushort_t* __restrict__ Tht,
                                                    ushort_t* __restrict__ Pb,
                                                    ushort_t* __restrict__ Qc,
                                                    uchar_t* __restrict__ R2f8) {
    __shared__ __align__(16) uchar_t th[3 * 64 * 128];    // 24576 B, [ko][f], 16B-chunk swizzled
    __shared__ __align__(16) uchar_t tbuf[26624];         // Q: 64*136 u16 (17408) + R2: 64*144 u8 (9216)
    ushort_t* tbq = (ushort_t*)tbuf;
    char* tbr = (char*)(tbuf + 17408);

    const int n0 = blockIdx.x * 128;
    const int t = blockIdx.y;
    const int b = blockIdx.z;
    const int tid = threadIdx.x;
    const int w = tid >> 6, lane = tid & 63, quad = lane >> 4, l15 = lane & 15;

    // Theta -> LDS, 16B chunks, phys chunk = c ^ (row&7) to break l15-stride-128B aliasing
#pragma unroll
    for (int i = 0; i < 3; ++i) {
        int chunk = i * 512 + tid;            // 0..1535
        int ko = chunk >> 3, c = chunk & 7;
        int phys = c ^ (ko & 7);
        const int4 v = *(const int4*)(Tht + ko * 64 + c * 8);
        *(int4*)(th + ko * 128 + phys * 16) = v;
    }

    // A-frags straight from global (row = n0 + w*16 + l15), fp32 -> bf16 in regs
    const float* xr = x + (((size_t)b * TT + t) * NNODE + n0 + w * 16 + l15) * FF;
    bf16x8 af[2];
#pragma unroll
    for (int ks = 0; ks < 2; ++ks) {
        const float4 v0 = *(const float4*)(xr + ks * 32 + quad * 8);
        const float4 v1 = *(const float4*)(xr + ks * 32 + quad * 8 + 4);
        u16x8 p;
        p[0] = f2bf(v0.x); p[1] = f2bf(v0.y); p[2] = f2bf(v0.z); p[3] = f2bf(v0.w);
        p[4] = f2bf(v1.x); p[5] = f2bf(v1.y); p[6] = f2bf(v1.z); p[7] = f2bf(v1.w);
        af[ks] = *(bf16x8*)&p;
    }
    __syncthreads();

    f32x4 acc[3][4];
#pragma unroll
    for (int k = 0; k < 3; ++k)
#pragma unroll
        for (int cb = 0; cb < 4; ++cb) acc[k][cb] = (f32x4){0.f, 0.f, 0.f, 0.f};

#pragma unroll
    for (int k = 0; k < 3; ++k)
#pragma unroll
        for (int ks = 0; ks < 2; ++ks)
#pragma unroll
            for (int cb = 0; cb < 4; ++cb) {
                const int o = cb * 16 + l15;
                const int c = (ks * 4 + quad) ^ (o & 7);
                const bf16x8 bfr = *(const bf16x8*)(th + (k * 64 + o) * 128 + c * 16);
                acc[k][cb] = __builtin_amdgcn_mfma_f32_16x16x32_bf16(af[ks], bfr, acc[k][cb], 0, 0, 0);
            }

    // P = R0 - R2, row-major (16 x 2B stores/lane, 32B segments per l15-group)
    ushort_t* Pbb = Pb + (((size_t)b * TT + t) * NNODE + n0) * OO;
#pragma unroll
    for (int cb = 0; cb < 4; ++cb)
#pragma unroll
        for (int r = 0; r < 4; ++r) {
            const int n = w * 16 + quad * 4 + r;
            const int o = cb * 16 + l15;
            Pbb[(size_t)n * OO + o] = f2bf(acc[0][cb][r] - acc[2][cb][r]);
        }

    // Q and R2 transposes, single LDS phase
#pragma unroll
    for (int cb = 0; cb < 4; ++cb)
#pragma unroll
        for (int r = 0; r < 4; ++r) {
            const int nl = w * 16 + quad * 4 + r;
            const int o = cb * 16 + l15;
            tbq[o * 136 + nl] = f2bf(acc[1][cb][r] - 2.0f * acc[2][cb][r]);
            tbr[o * 144 + nl] = (char)f2fp8(acc[2][cb][r]);
        }
    __syncthreads();

    {   // stream out: 8 threads per o-row
        const int o = tid >> 3, seg = tid & 7;
        ushort_t* qrow = Qc + ((size_t)b * TO + t * 64 + o) * NNODE + n0 + seg * 16;
        const ushort_t* sq = tbq + o * 136 + seg * 16;
        *(u16x8*)(qrow) = *(const u16x8*)(sq);
        *(u16x8*)(qrow + 8) = *(const u16x8*)(sq + 8);
        uchar_t* rrow = R2f8 + ((size_t)b * TO + t * 64 + o) * NNODE + n0 + seg * 16;
        *(int4*)rrow = *(const int4*)(tbr + o * 144 + seg * 16);
    }
}

// ------------------------------------------------------------- MX-fp8 GEMM
// D[r][c] = sum_k Aop[b][r][k] * Bop[b][c][k], both fp8 k-contiguous.
// E8 holds 2*A (batch-independent); lambda applied in the epilogue:
//   mode1: W = Q + (2/lam) * acc ;  mode2: out = relu(Pb + (1/lam) * acc).
// Both MX scale operands are 2^0.
// 1-D grid, XCD swizzle: bid%8 = XCD; all 48 tiles of a batch on one XCD.
// LDS 48 KB -> 3 blocks/CU (12 waves): A single-buffered, B double-buffered.
// Per K-step: stage B(kk+1) -> vmcnt(4) [retires A(kk),B(kk)] -> bar ->
//   ds_read A/B -> lgkmcnt(0) -> bar [all waves' reads done] ->
//   stage A(kk+1) into Abuf (lands under MFMA) -> MFMA.
// MODE 1 (W build):  r=c (768 rows), c=n.  A=R2f8, B=E8.
//    w = Qc[c][n] + (2/lam)*D;  Zf8[c][n] = fp8(w);  Pb -= w
// MODE 2 (output):   r=n (1024 rows), c=c.    A=E8, B=Zf8.
//    out = relu(bf16(Pb) + (1/lam)*D)   (Pb already holds P - W; D = (2A)@W)
template <int MODE>
__global__ __launch_bounds__(256, 3) void k_gemm8(const uchar_t* __restrict__ Aop, size_t aBS,
                                                  const uchar_t* __restrict__ Bop, size_t bBS,
                                                  const unsigned* __restrict__ lam,
                                                  const ushort_t* __restrict__ Qc,
                                                  uchar_t* __restrict__ Zf8,
                                                  ushort_t* __restrict__ Pbp,
                                                  float* __restrict__ outp) {
    __shared__ __align__(16) uchar_t smem[49152];   // A 16K @0, B0 16K @16K, B1 16K @32K; epi tb 34816
    const int bid = blockIdx.x;
    const int xcd = bid & 7, y = bid >> 3;
    const int tile = y % 48;
    const int b = xcd + 8 * (y / 48);
    const int tm = (MODE == 1) ? (tile >> 3) : (tile / 6);
    const int tn = (MODE == 1) ? (tile & 7) : (tile % 6);
    const int m0 = tm * 128, n0 = tn * 128;
    const int tid = threadIdx.x;
    const int w = tid >> 6, lane = tid & 63, quad = lane >> 4, l15 = lane & 15;
    const int wr = w >> 1, wc = w & 1;
    const uchar_t* Ab = Aop + (size_t)b * aBS + (size_t)m0 * NNODE;
    const uchar_t* Bb = Bop + (size_t)b * bBS + (size_t)n0 * NNODE;
    const float lamf = __uint_as_float(lam[b]);

    // staging: 16KB per tile, XOR-swizzled 16B chunks (phys = log ^ (row&7))
    int ldso[4];
    size_t goff[4];
#pragma unroll
    for (int i = 0; i < 4; ++i) {
        int slot = i * 256 + tid;
        int row = slot >> 3;
        int lc = (slot & 7) ^ (row & 7);
        ldso[i] = slot * 16;
        goff[i] = (size_t)row * NNODE + lc * 16;
    }

    f32x4 acc[4][4];
#pragma unroll
    for (int i = 0; i < 4; ++i)
#pragma unroll
        for (int j = 0; j < 4; ++j) acc[i][j] = (f32x4){0.f, 0.f, 0.f, 0.f};

    // prologue: A0 first, then B0 (vmcnt retire order relies on this)
#pragma unroll
    for (int i = 0; i < 4; ++i) gload16(Ab + goff[i], smem + ldso[i]);
#pragma unroll
    for (int i = 0; i < 4; ++i) gload16(Bb + goff[i], smem + 16384 + ldso[i]);

#pragma unroll
    for (int kk = 0; kk < 8; ++kk) {
        const uchar_t* At = smem;
        const uchar_t* Bt = smem + 16384 + ((kk & 1) << 14);
        uchar_t* Btn = smem + 16384 + (((kk & 1) ^ 1) << 14);
        if (kk < 7) {
            const int k0 = (kk + 1) << 7;
#pragma unroll
            for (int i = 0; i < 4; ++i) gload16(Bb + k0 + goff[i], Btn + ldso[i]);
            // outstanding: [B(kk):4][A(kk):4][B(kk+1):4] -> retire first 8
            asm volatile("s_waitcnt vmcnt(4)" ::: "memory");
        } else {
            asm volatile("s_waitcnt vmcnt(0)" ::: "memory");
        }
        __builtin_amdgcn_s_barrier();   // tile kk fully resident across all waves

        i32x8 af[4], bfr[4];
#pragma unroll
        for (int i = 0; i < 4; ++i) {
            const int m = wr * 64 + i * 16 + l15;
            const int n = wc * 64 + i * 16 + l15;
            const int4 alo = *(const int4*)(At + m * 128 + (((quad << 1)) ^ (m & 7)) * 16);
            const int4 ahi = *(const int4*)(At + m * 128 + (((quad << 1) | 1) ^ (m & 7)) * 16);
            const int4 blo = *(const int4*)(Bt + n * 128 + (((quad << 1)) ^ (n & 7)) * 16);
            const int4 bhi = *(const int4*)(Bt + n * 128 + (((quad << 1) | 1) ^ (n & 7)) * 16);
            af[i] = (i32x8){alo.x, alo.y, alo.z, alo.w, ahi.x, ahi.y, ahi.z, ahi.w};
            bfr[i] = (i32x8){blo.x, blo.y, blo.z, blo.w, bhi.x, bhi.y, bhi.z, bhi.w};
        }
        asm volatile("s_waitcnt lgkmcnt(0)" ::: "memory");
        __builtin_amdgcn_s_barrier();   // ALL waves' ds_reads done -> Abuf free
        if (kk < 7) {                   // restage A under the MFMA cluster
            const int k0 = (kk + 1) << 7;
#pragma unroll
            for (int i = 0; i < 4; ++i) gload16(Ab + k0 + goff[i], smem + ldso[i]);
        }
        __builtin_amdgcn_s_setprio(1);
#pragma unroll
        for (int i = 0; i < 4; ++i)
#pragma unroll
            for (int j = 0; j < 4; ++j)
                acc[i][j] = __builtin_amdgcn_mfma_scale_f32_16x16x128_f8f6f4(
                    af[i], bfr[j], acc[i][j], 0, 0, 0, SCL_ONE, 0, SCL_ONE);
        __builtin_amdgcn_s_setprio(0);
    }
    __syncthreads();   // epilogue reuses smem (tb overlaps buffers)

    if (MODE == 1) {
        const float c1 = 2.0f / lamf;
        ushort_t* tb = (ushort_t*)smem;   // [n_loc][c_loc], stride 136 (34816 B, fits)
        const ushort_t* Qb = Qc + (size_t)b * TO * NNODE;
        uchar_t* Zb = Zf8 + (size_t)b * TO * NNODE;
#pragma unroll
        for (int i = 0; i < 4; ++i)
#pragma unroll
            for (int r = 0; r < 4; ++r) {
                const int cl = wr * 64 + i * 16 + quad * 4 + r;
                const int c = m0 + cl;
#pragma unroll
                for (int j = 0; j < 4; ++j) {
                    const int nl = wc * 64 + j * 16 + l15;
                    const size_t zi = (size_t)c * NNODE + n0 + nl;
                    const float z = bf2f(Qb[zi]) + c1 * acc[i][j][r];
                    Zb[zi] = f2fp8(z);
                    tb[nl * 136 + cl] = f2bf(z);
                }
            }
        __syncthreads();
        // coalesced Pb -= w : each thread handles one (n-row, t-half) 128B segment
        const int t0 = m0 >> 6;
        const int row = tid >> 1, half = tid & 1;
        ushort_t* prow = Pbp + (((size_t)b * TT + t0 + half) * NNODE + n0 + row) * OO;
        const ushort_t* srow = tb + row * 136 + half * 64;
#pragma unroll
        for (int s = 0; s < 8; ++s) {
            u16x8 pv = *(const u16x8*)(prow + s * 8);
            u16x8 zv = *(const u16x8*)(srow + s * 8);
            u16x8 rv;
#pragma unroll
            for (int e = 0; e < 8; ++e) rv[e] = f2bf(bf2f(pv[e]) - bf2f(zv[e]));
            *(u16x8*)(prow + s * 8) = rv;
        }
    } else {
        const float c2 = 1.0f / lamf;
#pragma unroll
        for (int i = 0; i < 4; ++i)
#pragma unroll
            for (int r = 0; r < 4; ++r) {
                const int n = m0 + wr * 64 + i * 16 + quad * 4 + r;
#pragma unroll
                for (int j = 0; j < 4; ++j) {
                    const int c = n0 + wc * 64 + j * 16 + l15;
                    const int t = c >> 6, o = c & 63;
                    const size_t id = (((size_t)b * TT + t) * NNODE + n) * OO + o;
                    outp[id] = fmaxf(bf2f(Pbp[id]) + c2 * acc[i][j][r], 0.0f);
                }
            }
    }
}

extern "C" void kernel_launch(void* const* d_in, const int* in_sizes, int n_in,
                              void* d_out, int out_size, void* d_ws, size_t ws_size,
                              hipStream_t stream) {
    const float* x = (const float*)d_in[0];
    const float* A = (const float*)d_in[1];
    const float* Th = (const float*)d_in[2];
    float* out = (float*)d_out;
    char* ws = (char*)d_ws;

    // workspace (~176 MiB)
    unsigned* lam = (unsigned*)ws;                                   // 256 B
    uchar_t* E8 = (uchar_t*)(ws + 256);                              // 32 MiB
    uchar_t* R2f8 = E8 + (size_t)NB * NNODE * NNODE;                 // 24 MiB
    uchar_t* Zf8 = R2f8 + (size_t)NB * TO * NNODE;                   // 24 MiB
    ushort_t* Qc = (ushort_t*)(Zf8 + (size_t)NB * TO * NNODE);       // 48 MiB
    ushort_t* Pb = Qc + (size_t)NB * TO * NNODE;                     // 48 MiB
    ushort_t* Tht = Pb + (size_t)NB * TT * NNODE * OO;               // 24 KiB
    float* rsum = (float*)(Tht + 3 * 64 * 64);                       // 128 KiB

    k_prep<<<16384, 256, 0, stream>>>(A, rsum, E8);
    k_lmax<<<NB, 256, 0, stream>>>(rsum, lam);
    k_theta<<<48, 256, 0, stream>>>(Th, Tht);
    k_feature<<<dim3(8, 12, 32), 512, 0, stream>>>(x, Tht, Pb, Qc, R2f8);
    k_gemm8<1><<<1536, 256, 0, stream>>>(R2f8, (size_t)TO * NNODE,
                                         E8, (size_t)NNODE * NNODE,
                                         lam, Qc, Zf8, Pb, nullptr);
    k_gemm8<2><<<1536, 256, 0, stream>>>(E8, (size_t)NNODE * NNODE,
                                         Zf8, (size_t)TO * NNODE,
                                         lam, nullptr, nullptr, Pb, out);
}